// Round 3
// baseline (361.844 us; speedup 1.0000x reference)
//
#include <hip/hip_runtime.h>
#include <cstdint>
#include <cstddef>

// Problem constants (from reference: B,T,N = 512,1024,48)
constexpr int Bb = 512;
constexpr int Tt = 1024;
constexpr int Nn = 48;

__device__ __forceinline__ float readlane_f(float v, int i) {
    return __int_as_float(__builtin_amdgcn_readlane(__float_as_int(v), i));
}

// One wave (= one block) per batch element. Lane j < 48 owns state j.
//
// Scaled forward algorithm (exp-domain, lazy normalization):
//   a_{t+1}[j] = (sum_i a_t[i] * ET[i][j]) * exp(pot[t+1][j]) / a_t[0]
//   logZ accumulates log(a_t[0]); log_norm = log(sum_j a_final[j]) + logZ.
//
// Per-step critical path is pure VALU issue: 48 v_readlane (broadcast a[i]
// to SGPR) interleaved with 48 v_fma_f32 (SGPR x VGPR et column), 8
// accumulators (dep depth 6), reduce tree, 1 mul. No LDS on the chain.
__launch_bounds__(64)
__global__ void crf_nll_kernel(const float* __restrict__ pot,
                               const int*   __restrict__ ytrue,
                               const int*   __restrict__ lengths,
                               const float* __restrict__ trans,
                               float*       __restrict__ out)
{
    __shared__ float trans_lds[Nn * Nn];

    const int b      = blockIdx.x;
    const int lane   = threadIdx.x;
    const int lane_c = (lane < Nn) ? lane : (Nn - 1);   // clamped: in-bounds, no divergence
    const int len    = lengths[b];                      // in [1, T]

    for (int i = lane; i < Nn * Nn; i += 64) trans_lds[i] = trans[i];
    __syncthreads();

    const int*   yrow = ytrue + (size_t)b * Tt;
    const float* prow = pot + (size_t)b * Tt * Nn;

    // ---- Gold-path score: fully parallel pre-pass (off the sequential chain).
    float gold = 0.0f;
#pragma unroll
    for (int k = 0; k < Tt / 64; ++k) {
        const int   t    = lane + 64 * k;
        const int   yt   = yrow[t];
        const int   ytm1 = yrow[(t > 0) ? (t - 1) : 0];
        const float u    = prow[(size_t)t * Nn + yt];
        const float tr   = trans_lds[ytm1 * Nn + yt];
        const float m1   = (t < len) ? 1.0f : 0.0f;
        const float m2   = (t >= 1 && t < len) ? 1.0f : 0.0f;
        gold = fmaf(m1, u, gold);
        gold = fmaf(m2, tr, gold);
    }

    // et[i] = exp(trans[i][lane_c]) — lane's column of ET, 48 VGPRs.
    float et[Nn];
#pragma unroll
    for (int i = 0; i < Nn; ++i) et[i] = __expf(trans_lds[i * Nn + lane_c]);

    // ---- t = 0 init: a_0 = exp(pot0 - c0), logZ starts at c0.
    const float pot0 = prow[lane_c];
    const float c0   = readlane_f(pot0, 0);
    float a    = (lane < Nn) ? __expf(pot0 - c0) : 0.0f;
    float logz = c0;

    // Prefetch ring: rows t=1..8 (always in-bounds, T=1024)
    float p0 = prow[1 * Nn + lane_c];
    float p1 = prow[2 * Nn + lane_c];
    float p2 = prow[3 * Nn + lane_c];
    float p3 = prow[4 * Nn + lane_c];
    float p4 = prow[5 * Nn + lane_c];
    float p5 = prow[6 * Nn + lane_c];
    float p6 = prow[7 * Nn + lane_c];
    float p7 = prow[8 * Nn + lane_c];

    auto step = [&](float p) {
        // ep/r/logz: off the dot's issue tail; c reuses the i=0 readlane.
        const float ep = __expf(p);                 // p prefetched, no dep on a
        const float c  = readlane_f(a, 0);          // c = a_t[0] > 0
        const float r  = __builtin_amdgcn_rcpf(c);
        logz += __logf(c);
        const float f  = ep * r;

        float acc0 = 0.f, acc1 = 0.f, acc2 = 0.f, acc3 = 0.f;
        float acc4 = 0.f, acc5 = 0.f, acc6 = 0.f, acc7 = 0.f;
#pragma unroll
        for (int i = 0; i < Nn; i += 8) {
            acc0 = fmaf(readlane_f(a, i + 0), et[i + 0], acc0);
            acc1 = fmaf(readlane_f(a, i + 1), et[i + 1], acc1);
            acc2 = fmaf(readlane_f(a, i + 2), et[i + 2], acc2);
            acc3 = fmaf(readlane_f(a, i + 3), et[i + 3], acc3);
            acc4 = fmaf(readlane_f(a, i + 4), et[i + 4], acc4);
            acc5 = fmaf(readlane_f(a, i + 5), et[i + 5], acc5);
            acc6 = fmaf(readlane_f(a, i + 6), et[i + 6], acc6);
            acc7 = fmaf(readlane_f(a, i + 7), et[i + 7], acc7);
        }
        const float s = ((acc0 + acc1) + (acc2 + acc3)) +
                        ((acc4 + acc5) + (acc6 + acc7));   // s > 0
        a = s * f;   // lanes >= 48 replicate lane 47's column; masked at the end
    };

    int t = 1;
#define SLOT(P)                                                   \
    do {                                                          \
        step(P);                                                  \
        int tn = t + 8; if (tn > Tt - 1) tn = Tt - 1;             \
        P = prow[(size_t)tn * Nn + lane_c];                       \
        ++t;                                                      \
    } while (0)

    while (t + 8 <= len) {
        SLOT(p0); SLOT(p1); SLOT(p2); SLOT(p3);
        SLOT(p4); SLOT(p5); SLOT(p6); SLOT(p7);
    }
#undef SLOT
    while (t < len) {
        const float pc = prow[(size_t)t * Nn + lane_c];
        step(pc);
        ++t;
    }

    // log_norm = log(sum_j a[j]) + logz   (mask junk lanes >= 48)
    float se = (lane < Nn) ? a : 0.0f;
#pragma unroll
    for (int off = 32; off > 0; off >>= 1) se += __shfl_xor(se, off);
    const float log_norm = __logf(se) + logz;

    float g = gold;
#pragma unroll
    for (int off = 32; off > 0; off >>= 1) g += __shfl_xor(g, off);

    if (lane == 0) out[b] = log_norm - g;   // NLL = log_norm - seq_score
}

extern "C" void kernel_launch(void* const* d_in, const int* in_sizes, int n_in,
                              void* d_out, int out_size, void* d_ws, size_t ws_size,
                              hipStream_t stream)
{
    const float* pot    = (const float*)d_in[0];
    const int*   ytrue  = (const int*)  d_in[1];
    const int*   lens   = (const int*)  d_in[2];
    const float* trans  = (const float*)d_in[3];
    float*       out    = (float*)d_out;

    crf_nll_kernel<<<dim3(Bb), dim3(64), 0, stream>>>(pot, ytrue, lens, trans, out);
}

// Round 4
// 219.259 us; speedup vs baseline: 1.6503x; 1.6503x over previous
//
#include <hip/hip_runtime.h>
#include <cstdint>
#include <cstddef>

// Problem constants (from reference: B,T,N = 512,1024,48)
constexpr int Bb = 512;
constexpr int Tt = 1024;
constexpr int Nn = 48;
constexpr int Cc = 4;          // time-chunks per sequence (grid = B*C waves)
constexpr int Lc = Tt / Cc;    // 256 steps per chunk
constexpr int Wb = 96;         // burn-in steps (direction convergence; Hilbert
                               // contraction of diag(e^pot)*ET^T makes the
                               // incoming-direction error << 1e-5 by 96 steps)

typedef float f2 __attribute__((ext_vector_type(2)));
typedef float f4 __attribute__((ext_vector_type(4)));

__device__ __forceinline__ float readlane0(float v) {
    return __int_as_float(__builtin_amdgcn_readlane(__float_as_int(v), 0));
}

// One wave per (sequence, chunk). Lane j < 48 owns state j.
// Scaled forward in exp-domain (R2-proven step, 471 cyc latency):
//   c = a[0]; a' = (ET^T a) * exp(pot_t) / c;  g += log c
// Chunk telescoping (exact): G_c = -log a_in[0] + sum log c + log a_end[0]
// (last chunk: + log sum_j a_end instead). sum_c G_c = logZ.
__launch_bounds__(64)
__global__ void crf_nll_kernel(const float* __restrict__ pot,
                               const int*   __restrict__ ytrue,
                               const int*   __restrict__ lengths,
                               const float* __restrict__ trans,
                               float*       __restrict__ out)
{
    __shared__ __align__(16) float a_lds[64];
    __shared__ float trans_lds[Nn * Nn];

    const int b      = blockIdx.x >> 2;     // sequence
    const int c      = blockIdx.x & 3;      // chunk
    const int lane   = threadIdx.x;
    const int lane_c = (lane < Nn) ? lane : (Nn - 1);   // clamped: in-bounds, no divergence
    const int len    = lengths[b];                      // in [1, T]

    for (int i = lane; i < Nn * Nn; i += 64) trans_lds[i] = trans[i];
    __syncthreads();

    const int start = (c == 0) ? 1 : c * Lc;    // first step this chunk applies
    if (c > 0 && start >= len) return;          // chunk entirely past the sequence
    const int  end     = (len < (c + 1) * Lc) ? len : (c + 1) * Lc;
    const bool is_last = (end == len);          // unique chunk holding t = len-1

    const int*   yrow = ytrue + (size_t)b * Tt;
    const float* prow = pot + (size_t)b * Tt * Nn;

    // ---- Gold-path score: parallel pre-pass, chunk-0 wave only.
    float gold = 0.0f;
    if (c == 0) {
#pragma unroll
        for (int k = 0; k < Tt / 64; ++k) {
            const int   t    = lane + 64 * k;
            const int   yt   = yrow[t];
            const int   ytm1 = yrow[(t > 0) ? (t - 1) : 0];
            const float u    = prow[(size_t)t * Nn + yt];
            const float tr   = trans_lds[ytm1 * Nn + yt];
            const float m1   = (t < len) ? 1.0f : 0.0f;
            const float m2   = (t >= 1 && t < len) ? 1.0f : 0.0f;
            gold = fmaf(m1, u, gold);
            gold = fmaf(m2, tr, gold);
        }
    }

    // et column j resident in 48 VGPRs/lane (packed pairs for v_pk_fma_f32).
    f2 et2[Nn / 2];
#pragma unroll
    for (int k = 0; k < Nn / 2; ++k) {
        et2[k].x = __expf(trans_lds[(2 * k)     * Nn + lane_c]);
        et2[k].y = __expf(trans_lds[(2 * k + 1) * Nn + lane_c]);
    }

    // ---- Init at t0-1. Chunk 0 starts exactly from A_0 = exp(pot_0)
    // (scaled by c0, compensated in g). Chunks c>0 warm-start Wb steps early.
    const int   t0    = (c == 0) ? 1 : (start - Wb);   // t0-1 >= 159 for c>0
    const float pinit = prow[(size_t)(t0 - 1) * Nn + lane_c];
    const float shift = readlane0(pinit);
    float a = (lane < Nn) ? __expf(pinit - shift) : 0.0f;
    float g = (c == 0) ? shift : 0.0f;   // c==0: log-scale of A_0 vs a

    auto step = [&](float p, float accf) {
        a_lds[lane] = a;                            // broadcast via LDS
        const float cc = readlane0(a);              // a[0] > 0
        const float r  = __builtin_amdgcn_rcpf(cc);
        g = fmaf(accf, __logf(cc), g);              // branchless accumulate
        const float f  = __expf(p) * r;

        f2 a0 = {0.0f, 0.0f}, a1 = {0.0f, 0.0f};
        f2 a2 = {0.0f, 0.0f}, a3 = {0.0f, 0.0f};
#pragma unroll
        for (int m = 0; m < 6; ++m) {
            const f4 v0 = *(const f4*)(a_lds + 8 * m);
            const f4 v1 = *(const f4*)(a_lds + 8 * m + 4);
            f2 lo0; lo0.x = v0.x; lo0.y = v0.y;
            f2 hi0; hi0.x = v0.z; hi0.y = v0.w;
            f2 lo1; lo1.x = v1.x; lo1.y = v1.y;
            f2 hi1; hi1.x = v1.z; hi1.y = v1.w;
            a0 += lo0 * et2[4 * m];
            a1 += hi0 * et2[4 * m + 1];
            a2 += lo1 * et2[4 * m + 2];
            a3 += hi1 * et2[4 * m + 3];
        }
        const f2 s2 = (a0 + a1) + (a2 + a3);
        const float s = s2.x + s2.y;                // > 0
        a = s * f;
    };

    // Run steps t in [lo, hi) with an 8-deep prefetch ring.
    auto run = [&](int lo, int hi, float accf) {
        if (lo >= hi) return;
        float pr[8];
#pragma unroll
        for (int k = 0; k < 8; ++k) {
            int tt = lo + k; if (tt > Tt - 1) tt = Tt - 1;
            pr[k] = prow[(size_t)tt * Nn + lane_c];
        }
        int t = lo;
        while (t + 8 <= hi) {
#pragma unroll
            for (int k = 0; k < 8; ++k) {
                step(pr[k], accf);
                int tn = t + 8; if (tn > Tt - 1) tn = Tt - 1;
                pr[k] = prow[(size_t)tn * Nn + lane_c];
                ++t;
            }
        }
        // tail (<8 steps): 1-ahead prefetch
        float pc = prow[(size_t)((t > Tt - 1) ? (Tt - 1) : t) * Nn + lane_c];
        while (t < hi) {
            int tn = t + 1; if (tn > Tt - 1) tn = Tt - 1;
            const float pn = prow[(size_t)tn * Nn + lane_c];
            step(pc, accf);
            pc = pn;
            ++t;
        }
    };

    if (c > 0) {
        run(t0, start, 0.0f);                 // burn-in: converge direction, no logs
        g = -__logf(readlane0(a));            // -log a_in[0] (telescoping anchor)
    }
    run(start, end, 1.0f);                    // the chunk's own steps

    float G;
    if (is_last) {
        float se = (lane < Nn) ? a : 0.0f;    // mask junk lanes >= 48
#pragma unroll
        for (int off = 32; off > 0; off >>= 1) se += __shfl_xor(se, off);
        G = g + __logf(se);
    } else {
        G = g + __logf(readlane0(a));
    }

    if (c == 0) {
        float gg = gold;
#pragma unroll
        for (int off = 32; off > 0; off >>= 1) gg += __shfl_xor(gg, off);
        G -= gg;                              // fold gold score into chunk 0's term
    }

    if (lane == 0) atomicAdd(&out[b], G);     // out zeroed by memset node each launch
}

extern "C" void kernel_launch(void* const* d_in, const int* in_sizes, int n_in,
                              void* d_out, int out_size, void* d_ws, size_t ws_size,
                              hipStream_t stream)
{
    const float* pot    = (const float*)d_in[0];
    const int*   ytrue  = (const int*)  d_in[1];
    const int*   lens   = (const int*)  d_in[2];
    const float* trans  = (const float*)d_in[3];
    float*       out    = (float*)d_out;

    hipMemsetAsync(out, 0, (size_t)out_size * sizeof(float), stream);
    crf_nll_kernel<<<dim3(Bb * Cc), dim3(64), 0, stream>>>(pot, ytrue, lens, trans, out);
}